// Round 1
// baseline (144.617 us; speedup 1.0000x reference)
//
#include <hip/hip_runtime.h>
#include <hip/hip_bf16.h>

#define B_SZ 16
#define T_SZ 1024
#define D_SZ 384
#define MAX_DUR 4
#define OUT_LEN (T_SZ * MAX_DUR)   // 4096

// Kernel 1: per-row inclusive cumsum of ds into ws.
// One block per batch row; 256 threads x 4 elements (int4).
__global__ __launch_bounds__(256) void cumsum_kernel(const int* __restrict__ ds,
                                                     int* __restrict__ cs) {
    __shared__ int sums[256];
    const int b   = blockIdx.x;
    const int tid = threadIdx.x;

    int4 v = ((const int4*)(ds + b * T_SZ))[tid];
    const int s0 = v.x;
    const int s1 = s0 + v.y;
    const int s2 = s1 + v.z;
    const int s3 = s2 + v.w;

    sums[tid] = s3;
    __syncthreads();

    // Hillis-Steele inclusive scan over the 256 per-thread sums.
    int val = s3;
    for (int off = 1; off < 256; off <<= 1) {
        int other = (tid >= off) ? sums[tid - off] : 0;
        __syncthreads();
        val += other;
        sums[tid] = val;
        __syncthreads();
    }

    const int excl = val - s3;   // exclusive prefix for this thread's chunk
    int4 o;
    o.x = excl + s0;
    o.y = excl + s1;
    o.z = excl + s2;
    o.w = excl + s3;
    ((int4*)(cs + b * T_SZ))[tid] = o;
}

// Kernel 2: length-regulate. 4 frames per 384-thread block.
// Lane layout: lf = tid/96 (frame within block), col = tid%96 (float4 column).
// One lane per frame binary-searches cumsum; all lanes then copy via float4.
__global__ __launch_bounds__(384) void regulate_kernel(const float* __restrict__ xs,
                                                       const int* __restrict__ cs,
                                                       float* __restrict__ out) {
    __shared__ int sidx[4];
    const int tid = threadIdx.x;
    const int lf  = tid / 96;          // 0..3
    const int col = tid - lf * 96;     // 0..95

    const long long fbase = (long long)blockIdx.x * 4;   // first frame of block
    const int b = (int)(fbase >> 12);                    // fbase / 4096 (OUT_LEN)

    if (col == 0) {
        const int t = (int)(fbase & (OUT_LEN - 1)) + lf; // frame within sample
        const int* c = cs + b * T_SZ;
        const int total = c[T_SZ - 1];
        int idx;
        if (t >= total) {
            idx = -1;                                    // pad frame
        } else {
            // first i with c[i] > t  (searchsorted side='right')
            int lo = 0, hi = T_SZ;
            while (lo < hi) {
                const int mid = (lo + hi) >> 1;
                if (c[mid] <= t) lo = mid + 1; else hi = mid;
            }
            idx = lo;
        }
        sidx[lf] = idx;
    }
    __syncthreads();

    const int idx = sidx[lf];
    float4 v = make_float4(0.0f, 0.0f, 0.0f, 0.0f);      // PAD_VALUE
    if (idx >= 0) {
        v = ((const float4*)(xs + ((long long)b * T_SZ + idx) * D_SZ))[col];
    }
    const long long f = fbase + lf;
    ((float4*)(out + f * D_SZ))[col] = v;
}

extern "C" void kernel_launch(void* const* d_in, const int* in_sizes, int n_in,
                              void* d_out, int out_size, void* d_ws, size_t ws_size,
                              hipStream_t stream) {
    const float* xs = (const float*)d_in[0];
    const int*   ds = (const int*)d_in[1];
    float*       out = (float*)d_out;
    int*         cs  = (int*)d_ws;     // B*T ints = 64 KB of scratch

    cumsum_kernel<<<B_SZ, 256, 0, stream>>>(ds, cs);

    const int frames = B_SZ * OUT_LEN;            // 65536
    regulate_kernel<<<frames / 4, 384, 0, stream>>>(xs, cs, out);
}

// Round 2
// 132.505 us; speedup vs baseline: 1.0914x; 1.0914x over previous
//
#include <hip/hip_runtime.h>
#include <hip/hip_bf16.h>

#define B_SZ 16
#define T_SZ 1024
#define D_SZ 384
#define MAX_DUR 4
#define OUT_LEN (T_SZ * MAX_DUR)   // 4096

// Kernel 1: per-row cumsum of ds (in LDS) + scatter of the frame->token index
// map into ws. idxArr[b*OUT_LEN + t] = source token i for output frame t, or
// -1 for pad frames. One block per batch row; 256 threads x 4 tokens.
__global__ __launch_bounds__(256) void prep_kernel(const int* __restrict__ ds,
                                                   int* __restrict__ idxArr) {
    __shared__ int sums[256];
    __shared__ int cs[T_SZ + 1];   // exclusive-style: cs[0]=0, cs[i+1]=incl cumsum
    const int b   = blockIdx.x;
    const int tid = threadIdx.x;

    int4 v = ((const int4*)(ds + b * T_SZ))[tid];
    const int s0 = v.x;
    const int s1 = s0 + v.y;
    const int s2 = s1 + v.z;
    const int s3 = s2 + v.w;

    sums[tid] = s3;
    __syncthreads();

    // Hillis-Steele inclusive scan over 256 per-thread sums.
    int val = s3;
    for (int off = 1; off < 256; off <<= 1) {
        int other = (tid >= off) ? sums[tid - off] : 0;
        __syncthreads();
        val += other;
        sums[tid] = val;
        __syncthreads();
    }

    const int excl = val - s3;
    if (tid == 0) cs[0] = 0;
    cs[4 * tid + 1] = excl + s0;
    cs[4 * tid + 2] = excl + s1;
    cs[4 * tid + 3] = excl + s2;
    cs[4 * tid + 4] = excl + s3;
    __syncthreads();

    const int total = cs[T_SZ];
    int* row = idxArr + b * OUT_LEN;

    // Scatter: token i covers output frames [cs[i], cs[i+1]).
    #pragma unroll
    for (int j = 0; j < 4; ++j) {
        const int i  = 4 * tid + j;
        const int st = cs[i];
        const int en = cs[i + 1];
        for (int t = st; t < en; ++t) row[t] = i;
    }
    // Tail: pad frames get -1.
    for (int t = total + tid; t < OUT_LEN; t += 256) row[t] = -1;
}

// Kernel 2: barrier-free copy. 4 frames per 384-thread block.
// lf = tid/96 (frame within block), col = tid%96 (float4 column).
__global__ __launch_bounds__(384) void regulate_kernel(const float* __restrict__ xs,
                                                       const int* __restrict__ idxArr,
                                                       float* __restrict__ out) {
    const int tid = threadIdx.x;
    const int lf  = tid / 96;          // 0..3
    const int col = tid - lf * 96;     // 0..95

    const long long f = (long long)blockIdx.x * 4 + lf;  // global frame id
    const int b = (int)(f >> 12);                        // f / OUT_LEN

    const int idx = idxArr[f];         // same address for 96 lanes -> L1 broadcast
    float4 v = make_float4(0.0f, 0.0f, 0.0f, 0.0f);      // PAD_VALUE
    if (idx >= 0) {
        v = ((const float4*)(xs + ((long long)b * T_SZ + idx) * D_SZ))[col];
    }
    ((float4*)(out + f * D_SZ))[col] = v;
}

extern "C" void kernel_launch(void* const* d_in, const int* in_sizes, int n_in,
                              void* d_out, int out_size, void* d_ws, size_t ws_size,
                              hipStream_t stream) {
    const float* xs  = (const float*)d_in[0];
    const int*   ds  = (const int*)d_in[1];
    float*       out = (float*)d_out;
    int*         idxArr = (int*)d_ws;   // B*OUT_LEN ints = 256 KB of scratch

    prep_kernel<<<B_SZ, 256, 0, stream>>>(ds, idxArr);

    const int frames = B_SZ * OUT_LEN;  // 65536
    regulate_kernel<<<frames / 4, 384, 0, stream>>>(xs, idxArr, out);
}

// Round 3
// 129.105 us; speedup vs baseline: 1.1202x; 1.0263x over previous
//
#include <hip/hip_runtime.h>
#include <hip/hip_bf16.h>

#define B_SZ 16
#define T_SZ 1024
#define D_SZ 384
#define MAX_DUR 4
#define OUT_LEN (T_SZ * MAX_DUR)        // 4096
#define C4 (D_SZ / 4)                   // 96 float4 per frame
#define N4 (B_SZ * OUT_LEN * C4)        // 6291456 float4 total output

// Kernel 1: per-row cumsum of ds (in LDS) + scatter of the frame -> source
// float4-base-offset map into ws. srcArr[b*OUT_LEN + t] = (b*T + i)*96 where
// i is the source token for output frame t, or -1 for pad frames.
__global__ __launch_bounds__(256) void prep_kernel(const int* __restrict__ ds,
                                                   int* __restrict__ srcArr) {
    __shared__ int sums[256];
    __shared__ int cs[T_SZ + 1];   // cs[0]=0, cs[i+1]=inclusive cumsum
    const int b   = blockIdx.x;
    const int tid = threadIdx.x;

    int4 v = ((const int4*)(ds + b * T_SZ))[tid];
    const int s0 = v.x;
    const int s1 = s0 + v.y;
    const int s2 = s1 + v.z;
    const int s3 = s2 + v.w;

    sums[tid] = s3;
    __syncthreads();

    // Hillis-Steele inclusive scan over 256 per-thread sums.
    int val = s3;
    for (int off = 1; off < 256; off <<= 1) {
        int other = (tid >= off) ? sums[tid - off] : 0;
        __syncthreads();
        val += other;
        sums[tid] = val;
        __syncthreads();
    }

    const int excl = val - s3;
    if (tid == 0) cs[0] = 0;
    cs[4 * tid + 1] = excl + s0;
    cs[4 * tid + 2] = excl + s1;
    cs[4 * tid + 3] = excl + s2;
    cs[4 * tid + 4] = excl + s3;
    __syncthreads();

    const int total = cs[T_SZ];
    int* row = srcArr + b * OUT_LEN;

    // Scatter: token i covers output frames [cs[i], cs[i+1)).
    #pragma unroll
    for (int j = 0; j < 4; ++j) {
        const int i   = 4 * tid + j;
        const int st  = cs[i];
        const int en  = cs[i + 1];
        const int src = (b * T_SZ + i) * C4;    // float4 base of source row
        for (int t = st; t < en; ++t) row[t] = src;
    }
    // Tail: pad frames get -1.
    for (int t = total + tid; t < OUT_LEN; t += 256) row[t] = -1;
}

// Kernel 2: flat copy over out as float4 array. 256 threads x 4 independent
// float4s per thread (4x MLP), 6144 blocks. Consecutive lanes -> consecutive
// g -> coalesced srcArr read (<=2 distinct f per wave), contiguous gather,
// contiguous store.
__global__ __launch_bounds__(256) void regulate_kernel(const float4* __restrict__ xs4,
                                                       const int* __restrict__ srcArr,
                                                       float4* __restrict__ out4) {
    const int g0 = blockIdx.x * 1024 + threadIdx.x;
    #pragma unroll
    for (int k = 0; k < 4; ++k) {
        const int g   = g0 + k * 256;
        const int f   = g / 96;            // magic-mul div (compile-time const)
        const int col = g - f * 96;
        const int s   = srcArr[f];
        float4 v = make_float4(0.0f, 0.0f, 0.0f, 0.0f);   // PAD_VALUE
        if (s >= 0) v = xs4[s + col];
        out4[g] = v;
    }
}

extern "C" void kernel_launch(void* const* d_in, const int* in_sizes, int n_in,
                              void* d_out, int out_size, void* d_ws, size_t ws_size,
                              hipStream_t stream) {
    const float4* xs4 = (const float4*)d_in[0];
    const int*    ds  = (const int*)d_in[1];
    float4*       out4 = (float4*)d_out;
    int*          srcArr = (int*)d_ws;     // B*OUT_LEN ints = 256 KB scratch

    prep_kernel<<<B_SZ, 256, 0, stream>>>(ds, srcArr);

    regulate_kernel<<<N4 / 1024, 256, 0, stream>>>(xs4, srcArr, out4);
}

// Round 4
// 128.050 us; speedup vs baseline: 1.1294x; 1.0082x over previous
//
#include <hip/hip_runtime.h>
#include <hip/hip_bf16.h>

#define B_SZ 16
#define T_SZ 1024
#define D_SZ 384
#define MAX_DUR 4
#define OUT_LEN (T_SZ * MAX_DUR)            // 4096 frames per sample
#define C4 (D_SZ / 4)                       // 96 float4 per frame
#define PER_SAMPLE_F4 (OUT_LEN * C4)        // 393216 float4 per sample
#define BLOCKS_PER_SAMPLE 96                // each block: 4096 float4 = 64 KiB
#define ITERS 16                            // 16 x 256 = 4096 float4 per block

// Single fused kernel. Each block:
//  1. loads its sample's full duration row (4 KB, L2-hot after first touch),
//  2. scans it (Hillis-Steele over 256 per-thread partials),
//  3. scatters the frame -> source-float4-base map into LDS (16 KB),
//  4. streams its 64 KiB slice of the output: LDS idx -> float4 gather -> store.
// Redundant per-block scan is ~2k cycles, hidden by 8 resident blocks/CU.
__global__ __launch_bounds__(256) void lenreg_fused(const float4* __restrict__ xs4,
                                                    const int* __restrict__ ds,
                                                    float4* __restrict__ out4) {
    __shared__ int sums[256];
    __shared__ int map[OUT_LEN];   // frame -> src float4 base, or -1 for pad
    __shared__ int s_total;

    const int tid = threadIdx.x;
    const int b   = blockIdx.x / BLOCKS_PER_SAMPLE;
    const int blk = blockIdx.x - b * BLOCKS_PER_SAMPLE;

    // --- scan of this sample's durations (4 tokens per thread) ---
    int4 v = ((const int4*)(ds + b * T_SZ))[tid];
    const int s0 = v.x;
    const int s1 = s0 + v.y;
    const int s2 = s1 + v.z;
    const int s3 = s2 + v.w;

    sums[tid] = s3;
    __syncthreads();

    int val = s3;
    for (int off = 1; off < 256; off <<= 1) {
        int other = (tid >= off) ? sums[tid - off] : 0;
        __syncthreads();
        val += other;
        sums[tid] = val;
        __syncthreads();
    }
    const int excl = val - s3;     // exclusive prefix of this thread's chunk
    if (tid == 255) s_total = val; // grand total

    // --- scatter frame->src map (all boundary values are thread-local) ---
    const int srcBase = (b * T_SZ + 4 * tid) * C4;
    {
        int st = excl, en = excl + s0;
        for (int t = st; t < en; ++t) map[t] = srcBase;
        st = en; en = excl + s1;
        for (int t = st; t < en; ++t) map[t] = srcBase + C4;
        st = en; en = excl + s2;
        for (int t = st; t < en; ++t) map[t] = srcBase + 2 * C4;
        st = en; en = excl + s3;
        for (int t = st; t < en; ++t) map[t] = srcBase + 3 * C4;
    }
    __syncthreads();               // publishes scatter + s_total

    const int total = s_total;
    for (int t = total + tid; t < OUT_LEN; t += 256) map[t] = -1;
    __syncthreads();

    // --- copy phase: 4096 float4s for this block ---
    const int base = blk * (ITERS * 256);                  // float4 offset in sample
    float4* outp = out4 + (size_t)b * PER_SAMPLE_F4;
    #pragma unroll
    for (int k = 0; k < ITERS; ++k) {
        const int g   = base + k * 256 + tid;
        const int f   = g / C4;            // frame within sample (magic-mul div)
        const int col = g - f * C4;
        const int s   = map[f];            // LDS, <=2 distinct values per wave
        float4 o = make_float4(0.0f, 0.0f, 0.0f, 0.0f);    // PAD_VALUE
        if (s >= 0) o = xs4[s + col];
        outp[g] = o;
    }
}

extern "C" void kernel_launch(void* const* d_in, const int* in_sizes, int n_in,
                              void* d_out, int out_size, void* d_ws, size_t ws_size,
                              hipStream_t stream) {
    const float4* xs4 = (const float4*)d_in[0];
    const int*    ds  = (const int*)d_in[1];
    float4*       out4 = (float4*)d_out;

    lenreg_fused<<<B_SZ * BLOCKS_PER_SAMPLE, 256, 0, stream>>>(xs4, ds, out4);
}